// Round 9
// baseline (1450.422 us; speedup 1.0000x reference)
//
#include <hip/hip_runtime.h>
#include <hip/hip_bf16.h>

// QLSTM: T=512, B=256, D=128, H=256, P=128, GAMMA=1
// Phase 1 (MFMA GEMM): sx[r,p] = ||x_r||^2 + ||px_p||^2 - 2 x_r.px_p  (full Sx, f16, 32MB ws)
// Phase 2 (round 9): 256 WGs x 1024 threads (16 waves, 4/SIMD, 128-reg budget).
//   Diagnosis r2-r8: every 2-waves/SIMD variant stalls at ~4500 cyc/step (~50%
//   idle) regardless of ALU mix; the one issue-bound kernel (r2, 4 waves/SIMD)
//   matched static counts. So: maximize waves/SIMD and make per-wave state fit
//   128 VGPRs. Wave w owns h=[16w,16w+16) x ALL 4 gates -> weights 16 h8 = 64
//   VGPRs. Sh on the VALU (8 lanes/proto fdot2, fused |hx|^2) - no qfrag, no
//   long MFMA chain; MFMA pipe does gates only (16/wave, 4 indep 4-chains).
//   amdgpu_waves_per_eu(4,4) pins the 128-reg bucket (LDS is tiny; without it
//   the allocator targets 64 regs for a 2-WG occupancy the grid never uses).

#define TT 512
#define BB 256
#define DD 128
#define HH 256
#define PP 128
#define DHH 384

typedef _Float16 h2 __attribute__((ext_vector_type(2)));
typedef _Float16 h8 __attribute__((ext_vector_type(8)));
typedef float f4v __attribute__((ext_vector_type(4)));

union F4H { float4 f; h2 h[4]; };

__device__ __forceinline__ void pin_h8(h8& v) { asm volatile("" : "+v"(v)); }
__device__ __forceinline__ void pin_h2(h2& v) { asm volatile("" : "+v"(v)); }

// barrier with LDS-only drain: global loads/stores stay in flight.
__device__ __forceinline__ void bar_lds() {
  asm volatile("s_waitcnt lgkmcnt(0)" ::: "memory");
  __builtin_amdgcn_s_barrier();
}

__device__ __forceinline__ float fdot2f(h2 a, h2 b, float c) {
#if __has_builtin(__builtin_amdgcn_fdot2)
  return __builtin_amdgcn_fdot2(a, b, c, false);
#else
  return c + (float)a.x * (float)b.x + (float)a.y * (float)b.y;
#endif
}

__device__ __forceinline__ float sigm_f(float x) { return 1.f / (1.f + __expf(-x)); }
__device__ __forceinline__ float tanh_f(float x) { return 1.f - 2.f / (1.f + __expf(2.f * x)); }

__device__ __forceinline__ h8 pack_h8(float4 a, float4 b2, float s) {
  h8 v;
  v[0] = (_Float16)(s * a.x);  v[1] = (_Float16)(s * a.y);
  v[2] = (_Float16)(s * a.z);  v[3] = (_Float16)(s * a.w);
  v[4] = (_Float16)(s * b2.x); v[5] = (_Float16)(s * b2.y);
  v[6] = (_Float16)(s * b2.z); v[7] = (_Float16)(s * b2.w);
  return v;
}

// ---------------- Phase 1: Sx via MFMA f16 ----------------
__global__ __launch_bounds__(256, 2) void sx_kernel(const float* __restrict__ x,
                                                    const float* __restrict__ proto,
                                                    _Float16* __restrict__ sx) {
  __shared__ __align__(16) _Float16 qlds[PP * 136];   // -2*proto_x, f16
  __shared__ __align__(16) _Float16 xlds[64 * 136];   // x tile, f16
  __shared__ float pnlds[PP];
  __shared__ float xnlds[64];

  const int t = threadIdx.x;
  const int lane = t & 63;
  const int wv = t >> 6;          // wave 0..3 -> m-tile
  const int col = lane & 15;
  const int quad = lane >> 4;
  const int r0 = blockIdx.x * 256;

  // ---- stage q = -2*proto_x (f16) + pnorm ----
  {
    const int p = t >> 1;
    const int hh = t & 1;
    const float* src = proto + p * DHH + hh * 64;
    _Float16* dst = qlds + p * 136 + hh * 64;
    float pn = 0.f;
#pragma unroll
    for (int i = 0; i < 8; ++i) {
      float4 a = *(const float4*)(src + i * 8);
      float4 b = *(const float4*)(src + i * 8 + 4);
      pn = fmaf(a.x, a.x, fmaf(a.y, a.y, fmaf(a.z, a.z, fmaf(a.w, a.w, pn))));
      pn = fmaf(b.x, b.x, fmaf(b.y, b.y, fmaf(b.z, b.z, fmaf(b.w, b.w, pn))));
      *(h8*)(dst + i * 8) = pack_h8(a, b, -2.f);
    }
    pn += __shfl_xor(pn, 1);
    if (hh == 0) pnlds[p] = pn;
  }

  // ---- stage x tile 0 ----
  {
    const int m = t >> 2;
    const int q4 = t & 3;
    const float* xs = x + ((size_t)(r0 + m)) * DD + q4 * 32;
    _Float16* xd = xlds + m * 136 + q4 * 32;
    float xn = 0.f;
#pragma unroll
    for (int i = 0; i < 4; ++i) {
      float4 a = *(const float4*)(xs + i * 8);
      float4 b = *(const float4*)(xs + i * 8 + 4);
      xn = fmaf(a.x, a.x, fmaf(a.y, a.y, fmaf(a.z, a.z, fmaf(a.w, a.w, xn))));
      xn = fmaf(b.x, b.x, fmaf(b.y, b.y, fmaf(b.z, b.z, fmaf(b.w, b.w, xn))));
      *(h8*)(xd + i * 8) = pack_h8(a, b, 1.f);
    }
    xn += __shfl_xor(xn, 1);
    xn += __shfl_xor(xn, 2);
    if (q4 == 0) xnlds[m] = xn;
  }
  __syncthreads();

  float pn8[8];
#pragma unroll
  for (int nt = 0; nt < 8; ++nt) pn8[nt] = pnlds[nt * 16 + col];

  for (int tile = 0; tile < 4; ++tile) {
    h8 af[4];
#pragma unroll
    for (int kc = 0; kc < 4; ++kc)
      af[kc] = *(const h8*)(xlds + (wv * 16 + col) * 136 + kc * 32 + quad * 8);
    float xnq[4];
#pragma unroll
    for (int r = 0; r < 4; ++r) xnq[r] = xnlds[wv * 16 + quad * 4 + r];

#pragma unroll
    for (int nt = 0; nt < 8; ++nt) {
      f4v acc;
      acc[0] = pn8[nt]; acc[1] = pn8[nt]; acc[2] = pn8[nt]; acc[3] = pn8[nt];
#pragma unroll
      for (int kc = 0; kc < 4; ++kc) {
        h8 bf = *(const h8*)(qlds + (nt * 16 + col) * 136 + kc * 32 + quad * 8);
        acc = __builtin_amdgcn_mfma_f32_16x16x32_f16(af[kc], bf, acc, 0, 0, 0);
      }
#pragma unroll
      for (int r = 0; r < 4; ++r) {
        const int row = r0 + tile * 64 + wv * 16 + quad * 4 + r;
        sx[(size_t)row * PP + nt * 16 + col] = (_Float16)(acc[r] + xnq[r]);
      }
    }

    if (tile < 3) {
      __syncthreads();
      const int m = t >> 2;
      const int q4 = t & 3;
      const float* xs = x + ((size_t)(r0 + (tile + 1) * 64 + m)) * DD + q4 * 32;
      _Float16* xd = xlds + m * 136 + q4 * 32;
      float xn = 0.f;
#pragma unroll
      for (int i = 0; i < 4; ++i) {
        float4 a = *(const float4*)(xs + i * 8);
        float4 b = *(const float4*)(xs + i * 8 + 4);
        xn = fmaf(a.x, a.x, fmaf(a.y, a.y, fmaf(a.z, a.z, fmaf(a.w, a.w, xn))));
        xn = fmaf(b.x, b.x, fmaf(b.y, b.y, fmaf(b.z, b.z, fmaf(b.w, b.w, xn))));
        *(h8*)(xd + i * 8) = pack_h8(a, b, 1.f);
      }
      xn += __shfl_xor(xn, 1);
      xn += __shfl_xor(xn, 2);
      if (q4 == 0) xnlds[m] = xn;
      __syncthreads();
    }
  }
}

// ---------------- Phase 2: sequential recurrence (16 waves, 4/SIMD) ----------------
__global__ __launch_bounds__(1024)
__attribute__((amdgpu_waves_per_eu(4, 4)))
void rec_kernel(
    const _Float16* __restrict__ sx, const float* __restrict__ proto,
    const float* __restrict__ Wf, const float* __restrict__ bfv,
    const float* __restrict__ Wi, const float* __restrict__ biv,
    const float* __restrict__ Wg, const float* __restrict__ bgv,
    const float* __restrict__ Wo, const float* __restrict__ bov,
    float* __restrict__ out) {
  const int b = blockIdx.x;
  const int t = threadIdx.x;
  const int w = t >> 6;     // wave 0..15
  const int l = t & 63;
  const int lc = l & 15;    // gate C column
  const int lg = l >> 4;    // k-group 0..3

  // ---- gate weights: wave w owns h = 16w + lc, ALL 4 gates: 16 h8 = 64 VGPRs
  const int h = w * 16 + lc;
  const float* const Warr[4] = {Wf, Wi, Wg, Wo};
  const float* const barr[4] = {bfv, biv, bgv, bov};
  h8 wfrag[4][4];
  float bias[4];
#pragma unroll
  for (int g = 0; g < 4; ++g) {
    const float* row = Warr[g] + (size_t)h * PP;
    bias[g] = barr[g][h];
#pragma unroll
    for (int c = 0; c < 4; ++c) {
      float4 a = *(const float4*)(row + c * 32 + lg * 8);
      float4 b2 = *(const float4*)(row + c * 32 + lg * 8 + 4);
      wfrag[g][c] = pack_h8(a, b2, 1.f);
    }
  }
#pragma unroll
  for (int g = 0; g < 4; ++g)
#pragma unroll
    for (int c = 0; c < 4; ++c) pin_h8(wfrag[g][c]);

  // ---- Sh (VALU): 8 lanes per prototype, 32 dims each -> 16 h2 regs
  const int p = (w << 3) + (l >> 3);  // 16 waves x 8 = 128 protos
  const int cc = l & 7;               // dim chunk
  h2 ph[16];
  float pn = 0.f;
#pragma unroll
  for (int j = 0; j < 16; ++j) {
    float2 a = *(const float2*)(proto + (size_t)p * DHH + DD + cc * 32 + 2 * j);
    pn = fmaf(a.x, a.x, pn);
    pn = fmaf(a.y, a.y, pn);
    h2 u; u.x = (_Float16)(-2.f * a.x); u.y = (_Float16)(-2.f * a.y); ph[j] = u;
  }
#pragma unroll
  for (int j = 0; j < 16; ++j) pin_h2(ph[j]);
  pn += __shfl_xor(pn, 1);
  pn += __shfl_xor(pn, 2);
  pn += __shfl_xor(pn, 4);

  __shared__ __align__(16) _Float16 hxlds[HH];  // hx, f16
  __shared__ __align__(16) _Float16 klds[PP];   // k, f16

  if (t < HH) hxlds[t] = (_Float16)0.f;
  float cx = 0.f, hx = 0.f;
  __syncthreads();

  float sx_next = (float)sx[(size_t)b * PP + p];
  const _Float16* hxc = hxlds + cc * 32;
  const f4v zacc = {0.f, 0.f, 0.f, 0.f};

  for (int step = 0; step < TT; ++step) {
    // ---- Sh + |hx|^2 (VALU fdot2) + k ----
    const float sx_cur = sx_next;
    const int nst = (step + 1 < TT) ? (step + 1) : (TT - 1);
    sx_next = (float)sx[((size_t)nst * BB + b) * PP + p];

    float dA = 0.f, dB = 0.f, sA = 0.f, sB = 0.f;
#pragma unroll
    for (int j4 = 0; j4 < 4; ++j4) {
      F4H u; u.f = *(const float4*)(hxc + j4 * 8);
      dA = fdot2f(u.h[0], ph[4 * j4 + 0], dA);
      sA = fdot2f(u.h[0], u.h[0], sA);
      dB = fdot2f(u.h[1], ph[4 * j4 + 1], dB);
      sB = fdot2f(u.h[1], u.h[1], sB);
      dA = fdot2f(u.h[2], ph[4 * j4 + 2], dA);
      sA = fdot2f(u.h[2], u.h[2], sA);
      dB = fdot2f(u.h[3], ph[4 * j4 + 3], dB);
      sB = fdot2f(u.h[3], u.h[3], sB);
    }
    float dot = dA + dB;          // -2 hx.ph (this lane's 32 dims)
    float sq = sA + sB;           // |hx|^2 partial
    dot += __shfl_xor(dot, 1); sq += __shfl_xor(sq, 1);
    dot += __shfl_xor(dot, 2); sq += __shfl_xor(sq, 2);
    dot += __shfl_xor(dot, 4); sq += __shfl_xor(sq, 4);

    const float d2 = sq + dot + pn + sx_cur;
    const float kk = __expf(-d2);
    if (cc == 0) klds[p] = (_Float16)kk;
    bar_lds();  // k ready

    // ---- gates: 4 gates x K=128 (4 indep 4-chains of MFMA), M=1 broadcast ----
    f4v acc[4];
#pragma unroll
    for (int g = 0; g < 4; ++g) { acc[g] = zacc; acc[g][0] = bias[g]; }
#pragma unroll
    for (int c = 0; c < 4; ++c) {
      h8 kf = *(const h8*)(klds + c * 32 + lg * 8);
#pragma unroll
      for (int g = 0; g < 4; ++g)
        acc[g] = __builtin_amdgcn_mfma_f32_16x16x32_f16(kf, wfrag[g][c], acc[g], 0, 0, 0);
    }

    // ---- activations + in-register cell update (all lanes valid dups) ----
    const float f_ = sigm_f(acc[0][0]);
    const float i_ = sigm_f(acc[1][0]);
    const float g_ = tanh_f(acc[2][0]);
    const float o_ = sigm_f(acc[3][0]);
    cx = fmaf(f_, cx, i_ * g_);
    hx = o_ * tanh_f(cx);

    if (l < 16) {
      out[((size_t)step * BB + b) * HH + h] = hx;
      hxlds[h] = (_Float16)hx;
    }
    bar_lds();  // hx ready for next step
  }

  if (l < 16) {
    const size_t base = (size_t)TT * BB * HH;
    out[base + (size_t)b * HH + h] = hx;
    out[base + (size_t)BB * HH + (size_t)b * HH + h] = cx;
  }
}

extern "C" void kernel_launch(void* const* d_in, const int* in_sizes, int n_in,
                              void* d_out, int out_size, void* d_ws, size_t ws_size,
                              hipStream_t stream) {
  const float* x     = (const float*)d_in[0];
  const float* proto = (const float*)d_in[1];
  const float* Wf = (const float*)d_in[2];
  const float* bf = (const float*)d_in[3];
  const float* Wi = (const float*)d_in[4];
  const float* bi = (const float*)d_in[5];
  const float* Wg = (const float*)d_in[6];
  const float* bg = (const float*)d_in[7];
  const float* Wo = (const float*)d_in[8];
  const float* bo = (const float*)d_in[9];
  float* out = (float*)d_out;
  _Float16* sxbuf = (_Float16*)d_ws;  // T*B*P*2 = 32 MB

  sx_kernel<<<512, 256, 0, stream>>>(x, proto, sxbuf);
  rec_kernel<<<BB, 1024, 0, stream>>>(sxbuf, proto, Wf, bf, Wi, bi, Wg, bg, Wo, bo, out);
}